// Round 1
// 1264.153 us; speedup vs baseline: 1.1057x; 1.1057x over previous
//
#include <hip/hip_runtime.h>
#include <cstddef>

// Problem constants (from reference)
#define NN 100000
#define NE 1600000
#define NH 5
#define NC 12
#define HC 60     // NH*NC
#define FN 128
#define FE 32
#define HID 16
#define NCLS 2

// ---------------------------------------------------------------------------
// qkvs: computes q,k,v,skip = X @ W? + b?  for 4 weight matrices [DIN,60].
// One block = 8 nodes, 256 threads; threads 0..239 each own (matrix, col).
// X rows are wave-uniform -> compiler scalarizes to s_load (SMEM pipe),
// removing the LDS round-trip (1024 ds_reads/thread) and both barriers.
// NN == 8*12500 exactly, so no bounds checks.
// ---------------------------------------------------------------------------
template<int DIN>
__global__ __launch_bounds__(256) void qkvs_kernel(
    const float* __restrict__ X,
    const float* __restrict__ Wq, const float* __restrict__ bq,
    const float* __restrict__ Wk, const float* __restrict__ bk,
    const float* __restrict__ Wv, const float* __restrict__ bv,
    const float* __restrict__ Ws, const float* __restrict__ bs,
    float* __restrict__ q, float* __restrict__ k,
    float* __restrict__ v, float* __restrict__ s)
{
    constexpr int NB = 8;
    const int n0 = blockIdx.x * NB;
    const int j = threadIdx.x;
    if (j >= 240) return;
    const int mat = j / 60, col = j - mat * 60;
    const float* W; const float* b; float* out;
    switch (mat) {
        case 0:  W = Wq; b = bq; out = q; break;
        case 1:  W = Wk; b = bk; out = k; break;
        case 2:  W = Wv; b = bv; out = v; break;
        default: W = Ws; b = bs; out = s; break;
    }
    const float* __restrict__ xr = X + (size_t)n0 * DIN;   // wave-uniform base
    float acc[NB];
    #pragma unroll
    for (int m = 0; m < NB; ++m) acc[m] = 0.f;
    #pragma unroll 4
    for (int r = 0; r < DIN; ++r) {
        const float w = W[r * 60 + col];                    // coalesced vector load
        #pragma unroll
        for (int m = 0; m < NB; ++m)
            acc[m] = fmaf(xr[(size_t)m * DIN + r], w, acc[m]);  // s_load operand
    }
    const float bb = b[col];
    #pragma unroll
    for (int m = 0; m < NB; ++m)
        out[(size_t)(n0 + m) * 60 + col] = acc[m] + bb;
}

// ---------------------------------------------------------------------------
// CSR build: histogram of dst -> exclusive scan -> scatter edge ids (+src ids)
// ---------------------------------------------------------------------------
__global__ __launch_bounds__(256) void hist_kernel(
    const int* __restrict__ ei, int* __restrict__ cnt)
{
    const int e = blockIdx.x * 256 + threadIdx.x;
    if (e < NE) atomicAdd(&cnt[ei[NE + e]], 1);
}

__global__ __launch_bounds__(1024) void scan1_kernel(
    const int* __restrict__ cnt, int* __restrict__ excl, int* __restrict__ bsum)
{
    __shared__ int sh[1024];
    const int i = blockIdx.x * 1024 + threadIdx.x;
    const int v = (i < NN) ? cnt[i] : 0;
    sh[threadIdx.x] = v;
    __syncthreads();
    for (int off = 1; off < 1024; off <<= 1) {
        const int t = (threadIdx.x >= off) ? sh[threadIdx.x - off] : 0;
        __syncthreads();
        sh[threadIdx.x] += t;
        __syncthreads();
    }
    if (i < NN) excl[i] = sh[threadIdx.x] - v;     // block-local exclusive
    if (threadIdx.x == 1023) bsum[blockIdx.x] = sh[1023];
}

__global__ void scan2_kernel(int* __restrict__ bsum, int nb, int* __restrict__ start)
{
    if (threadIdx.x == 0 && blockIdx.x == 0) {
        int acc = 0;
        for (int b = 0; b < nb; ++b) { const int t = bsum[b]; bsum[b] = acc; acc += t; }
        start[NN] = acc;   // == NE
    }
}

__global__ __launch_bounds__(1024) void scan3_kernel(
    int* __restrict__ start, const int* __restrict__ bsum)
{
    const int i = blockIdx.x * 1024 + threadIdx.x;
    if (i < NN) start[i] += bsum[blockIdx.x];
}

__global__ __launch_bounds__(256) void scatter_kernel(
    const int* __restrict__ ei, int* __restrict__ cursor,
    int* __restrict__ perm, int* __restrict__ srcs)
{
    const int e = blockIdx.x * 256 + threadIdx.x;
    if (e >= NE) return;
    const int d = ei[NE + e];
    const int pos = atomicAdd(&cursor[d], 1);
    perm[pos] = e;
    srcs[pos] = ei[e];   // materialize src: kills one dependent load in agg
}

// ---------------------------------------------------------------------------
// permea: eaP[slot] = ea[perm[slot]]  (CSR order). Gather-read, coalesced
// write. Shared by BOTH layers (doesn't involve We). Makes the agg ea loads
// a linear function of the loop counter -> deep wave-uniform s_load pipeline.
// Thread = (slot, quarter-row); NE*8 threads, exact grid.
// ---------------------------------------------------------------------------
__global__ __launch_bounds__(256) void permea_kernel(
    const int* __restrict__ perm, const float* __restrict__ ea,
    float* __restrict__ eaP)
{
    const int t = blockIdx.x * 256 + threadIdx.x;
    const int slot = t >> 3, r4 = t & 7;
    const int e = perm[slot];
    const float4 val = ((const float4*)(ea + (size_t)e * FE))[r4];
    ((float4*)(eaP + (size_t)slot * FE))[r4] = val;
}

// ---------------------------------------------------------------------------
// Aggregation (gather, zero atomics): one wave per dst node, lane = channel hc.
// LIN=1: ea is eaP in CSR order (linear, wave-uniform s_loads, no broadcast).
// LIN=0: fallback when workspace too small (old perm-indexed path).
// src ids extracted with v_readlane (SGPR result -> SALU address math),
// k/v prefetched 2 edges ahead, ea 1 edge ahead.
// ---------------------------------------------------------------------------
template<bool LIN>
__global__ __launch_bounds__(256) void agg_kernel(
    const int* __restrict__ perm, const int* __restrict__ srcs,
    const int* __restrict__ start,
    const float* __restrict__ ea, const float* __restrict__ We,
    const float* __restrict__ q, const float* __restrict__ k,
    const float* __restrict__ v, const float* __restrict__ sk,
    float* __restrict__ hout)
{
    const int wv    = threadIdx.x >> 6;
    const int lane  = threadIdx.x & 63;
    const int n     = blockIdx.x * 4 + wv;
    const int hc    = (lane < 60) ? lane : 0;
    const int hd    = hc / NC;          // head 0..4
    const int hbase = hd * NC;          // head's first lane
    const int c     = hc - hbase;       // channel within head, 0..11

    // Shuffle source lanes for the 12-lane head reduction.
    const int r1 = hbase + ((c + 6) % 12);
    const int r2 = hbase + ((c + 3) % 12);
    const int r3 = hbase + ((c + 1) % 3);
    const int r4 = hbase + ((c + 2) % 3);

    // This lane's We column (fixed for whole kernel): 32 registers.
    float Wcol[FE];
    #pragma unroll
    for (int r = 0; r < FE; ++r) Wcol[r] = We[r * 60 + hc];

    const float qv = q[(size_t)n * 60 + hc];
    const float sv = sk[(size_t)n * 60 + hc];

    const int s0 = __builtin_amdgcn_readfirstlane(start[n]);
    const int s1 = __builtin_amdgcn_readfirstlane(start[n + 1]);

    float acc = 0.f, den = 0.f;

    auto compute = [&](const float (&EA)[FE], float KV, float VV) {
        float e0 = 0.f, e1 = 0.f;
        #pragma unroll
        for (int r = 0; r < FE; r += 2) {
            e0 = fmaf(EA[r],     Wcol[r],     e0);
            e1 = fmaf(EA[r + 1], Wcol[r + 1], e1);
        }
        const float eacc = e0 + e1;
        const float p  = qv * (KV + eacc);
        const float f1 = p  + __shfl(p,  r1);
        const float f2 = f1 + __shfl(f1, r2);
        const float a  = f2 + __shfl(f2, r3) + __shfl(f2, r4);
        const float w  = __expf(fmaf(a, 0.28867513459481287f, -20.0f));
        acc = fmaf(w, VV + eacc, acc);
        den += w;
    };

    for (int c0 = s0; c0 < s1; c0 += 64) {
        const int cnt = min(64, s1 - c0);

        // One coalesced load: lane j holds src (and edge id in fallback) for slot c0+j.
        int myE = 0, myS = 0;
        if (c0 + lane < s1) {
            myS = srcs[c0 + lane];
            if (!LIN) myE = perm[c0 + lane];
        }

        float eaA[FE], eaB[FE];
        float kA = 0.f, vA = 0.f, kB = 0.f, vB = 0.f;
        float kC = 0.f, vC = 0.f, kD = 0.f, vD = 0.f;

        {   // prologue: kv for edges 0,1; ea for edge 0
            const int sA = __builtin_amdgcn_readlane(myS, 0);
            kA = k[(size_t)sA * 60 + hc];
            vA = v[(size_t)sA * 60 + hc];
            if (cnt > 1) {
                const int sB = __builtin_amdgcn_readlane(myS, 1);
                kB = k[(size_t)sB * 60 + hc];
                vB = v[(size_t)sB * 60 + hc];
            }
            const float* __restrict__ er = LIN
                ? (ea + (size_t)c0 * FE)
                : (ea + (size_t)__builtin_amdgcn_readlane(myE, 0) * FE);
            #pragma unroll
            for (int r = 0; r < FE; ++r) eaA[r] = er[r];
        }

        for (int t = 0; t < cnt; t += 2) {
            if (t + 1 < cnt) {          // ea for edge t+1
                const float* __restrict__ er = LIN
                    ? (ea + (size_t)(c0 + t + 1) * FE)
                    : (ea + (size_t)__builtin_amdgcn_readlane(myE, t + 1) * FE);
                #pragma unroll
                for (int r = 0; r < FE; ++r) eaB[r] = er[r];
            }
            if (t + 2 < cnt) {          // kv prefetch distance 2
                const int sC = __builtin_amdgcn_readlane(myS, t + 2);
                kC = k[(size_t)sC * 60 + hc];
                vC = v[(size_t)sC * 60 + hc];
            }
            compute(eaA, kA, vA);
            if (t + 2 < cnt) {          // ea for edge t+2
                const float* __restrict__ er = LIN
                    ? (ea + (size_t)(c0 + t + 2) * FE)
                    : (ea + (size_t)__builtin_amdgcn_readlane(myE, t + 2) * FE);
                #pragma unroll
                for (int r = 0; r < FE; ++r) eaA[r] = er[r];
            }
            if (t + 3 < cnt) {
                const int sD = __builtin_amdgcn_readlane(myS, t + 3);
                kD = k[(size_t)sD * 60 + hc];
                vD = v[(size_t)sD * 60 + hc];
            }
            if (t + 1 < cnt) compute(eaB, kB, vB);
            kA = kC; vA = vC; kB = kD; vB = vD;
        }
    }

    if (lane < 60)
        hout[(size_t)n * 60 + hc] = fmaxf(acc / (den + 1e-16f) + sv, 0.f);
}

// ---------------------------------------------------------------------------
// MLP head: out = relu(h @ W1 + b1) @ W2 + b2     (one thread per node)
// ---------------------------------------------------------------------------
__global__ __launch_bounds__(256) void mlp_kernel(
    const float* __restrict__ h,
    const float* __restrict__ W1, const float* __restrict__ b1,
    const float* __restrict__ W2, const float* __restrict__ b2,
    float* __restrict__ out)
{
    __shared__ float sW1[60 * HID];
    __shared__ float sb1[HID];
    __shared__ float sW2[HID * NCLS];
    __shared__ float sb2[NCLS];
    for (int i = threadIdx.x; i < 60 * HID; i += 256) sW1[i] = W1[i];
    if (threadIdx.x < HID)        sb1[threadIdx.x] = b1[threadIdx.x];
    if (threadIdx.x < HID * NCLS) sW2[threadIdx.x] = W2[threadIdx.x];
    if (threadIdx.x < NCLS)       sb2[threadIdx.x] = b2[threadIdx.x];
    __syncthreads();

    const int n = blockIdx.x * 256 + threadIdx.x;
    if (n >= NN) return;
    const float* __restrict__ hr = h + (size_t)n * 60;
    float hv[60];
    #pragma unroll
    for (int i = 0; i < 15; ++i) {
        const float4 t = ((const float4*)hr)[i];
        hv[4 * i + 0] = t.x; hv[4 * i + 1] = t.y;
        hv[4 * i + 2] = t.z; hv[4 * i + 3] = t.w;
    }
    float o0 = sb2[0], o1 = sb2[1];
    for (int j = 0; j < HID; ++j) {
        float t = sb1[j];
        #pragma unroll
        for (int i = 0; i < 60; ++i) t = fmaf(hv[i], sW1[i * HID + j], t);
        t = fmaxf(t, 0.f);
        o0 = fmaf(t, sW2[2 * j + 0], o0);
        o1 = fmaf(t, sW2[2 * j + 1], o1);
    }
    out[(size_t)n * 2 + 0] = o0;
    out[(size_t)n * 2 + 1] = o1;
}

// ---------------------------------------------------------------------------
extern "C" void kernel_launch(void* const* d_in, const int* in_sizes, int n_in,
                              void* d_out, int out_size, void* d_ws, size_t ws_size,
                              hipStream_t stream)
{
    const float* x   = (const float*)d_in[0];
    const int*   ei  = (const int*)  d_in[1];
    const float* ea  = (const float*)d_in[2];
    const float* Wq1 = (const float*)d_in[3];  const float* bq1 = (const float*)d_in[4];
    const float* Wk1 = (const float*)d_in[5];  const float* bk1 = (const float*)d_in[6];
    const float* Wv1 = (const float*)d_in[7];  const float* bv1 = (const float*)d_in[8];
    const float* We1 = (const float*)d_in[9];
    const float* Ws1 = (const float*)d_in[10]; const float* bs1 = (const float*)d_in[11];
    const float* Wq2 = (const float*)d_in[12]; const float* bq2 = (const float*)d_in[13];
    const float* Wk2 = (const float*)d_in[14]; const float* bk2 = (const float*)d_in[15];
    const float* Wv2 = (const float*)d_in[16]; const float* bv2 = (const float*)d_in[17];
    const float* We2 = (const float*)d_in[18];
    const float* Ws2 = (const float*)d_in[19]; const float* bs2 = (const float*)d_in[20];
    const float* W1  = (const float*)d_in[21]; const float* b1  = (const float*)d_in[22];
    const float* W2  = (const float*)d_in[23]; const float* b2  = (const float*)d_in[24];
    float* out = (float*)d_out;

    // workspace layout: [ints][pad->256B][5 float bufs NN*60][eaP NE*32]
    int* cnt    = (int*)d_ws;             // NN
    int* startp = cnt + NN;               // NN+1
    int* cursor = startp + NN + 1;        // NN
    int* bsum   = cursor + NN;            // 128
    int* perm   = bsum + 128;             // NE
    int* srcs   = perm + NE;              // NE
    const size_t int_bytes = (size_t)(3 * NN + 1 + 128 + 2 * NE) * sizeof(int);
    const size_t f_off = (int_bytes + 255) & ~(size_t)255;
    const size_t NHC = (size_t)NN * 60;
    float* qb = (float*)((char*)d_ws + f_off);
    float* kb = qb + NHC;
    float* vb = kb + NHC;
    float* sb = vb + NHC;
    float* h0 = sb + NHC;                 // layer1 out; overwritten by layer2 out
    float* eaP = h0 + NHC;                // NE*32 floats (CSR-ordered edge_attr)
    const size_t need = f_off + 5 * NHC * sizeof(float) + (size_t)NE * FE * sizeof(float);
    const bool lin = ws_size >= need;

    const int qkvs_blocks = NN / 8;                // 12500 exact
    const int e256_blocks = NE / 256;              // 6250 exact
    const int scan_blocks = (NN + 1023) / 1024;    // 98
    const int agg_blocks  = NN / 4;                // 25000 exact
    const int mlp_blocks  = (NN + 255) / 256;      // 391
    const int perm_blocks = NE * 8 / 256;          // 50000 exact

    // ---- CSR build (once, shared by both layers) ----
    hipMemsetAsync(cnt, 0, (size_t)NN * sizeof(int), stream);
    hist_kernel<<<e256_blocks, 256, 0, stream>>>(ei, cnt);
    scan1_kernel<<<scan_blocks, 1024, 0, stream>>>(cnt, startp, bsum);
    scan2_kernel<<<1, 64, 0, stream>>>(bsum, scan_blocks, startp);
    scan3_kernel<<<scan_blocks, 1024, 0, stream>>>(startp, bsum);
    hipMemcpyAsync(cursor, startp, (size_t)NN * sizeof(int),
                   hipMemcpyDeviceToDevice, stream);
    scatter_kernel<<<e256_blocks, 256, 0, stream>>>(ei, cursor, perm, srcs);
    if (lin)
        permea_kernel<<<perm_blocks, 256, 0, stream>>>(perm, ea, eaP);

    // ---- layer 1 ----
    qkvs_kernel<FN><<<qkvs_blocks, 256, 0, stream>>>(
        x, Wq1, bq1, Wk1, bk1, Wv1, bv1, Ws1, bs1, qb, kb, vb, sb);
    if (lin)
        agg_kernel<true><<<agg_blocks, 256, 0, stream>>>(
            perm, srcs, startp, eaP, We1, qb, kb, vb, sb, h0);
    else
        agg_kernel<false><<<agg_blocks, 256, 0, stream>>>(
            perm, srcs, startp, ea, We1, qb, kb, vb, sb, h0);

    // ---- layer 2 ----
    qkvs_kernel<HC><<<qkvs_blocks, 256, 0, stream>>>(
        h0, Wq2, bq2, Wk2, bk2, Wv2, bv2, Ws2, bs2, qb, kb, vb, sb);
    if (lin)
        agg_kernel<true><<<agg_blocks, 256, 0, stream>>>(
            perm, srcs, startp, eaP, We2, qb, kb, vb, sb, h0);
    else
        agg_kernel<false><<<agg_blocks, 256, 0, stream>>>(
            perm, srcs, startp, ea, We2, qb, kb, vb, sb, h0);   // h0 reuse is safe

    // ---- MLP head ----
    mlp_kernel<<<mlp_blocks, 256, 0, stream>>>(h0, W1, b1, W2, b2, out);
}